// Round 15
// baseline (506.628 us; speedup 1.0000x reference)
//
#include <hip/hip_runtime.h>
#include <hip/hip_bf16.h>

// GraphProp R24 (resubmit; previous round failed on container acquisition,
// not on the kernel). R23 base (best: 488us; top-5 all gi-GEMM ~51us).
// gi and gh are artificially serialized (gh needs only hv). R24 merges
// them into ONE dispatch: 2346 blocks, mode = wid&1 (fine interleave ->
// gi/gh balanced per XCD), sub = wid>>1 (contiguous tiles per XCD for
// L2). gi's block-wave tail fills with light gh blocks; one dispatch
// boundary vanishes. NOT the refuted fusion: per-block code is the
// byte-identical R23 body (shared gemm_body), no extra live state.
// Merged mode needs S/gi/gh in separate buffers (+25.6MB, 142.4MB
// total); ws_size is CHECKED at launch and we fall back to the exact
// R23 serial layout/kernels if it doesn't fit.
// Everything else (GG=512 build, R23 bucket_sort, R21 gather/gate/wc):
// byte-identical to R23.

#define NN 50000
#define NE 1600000
#define HH 128
#define TT 2
#define NB 1563   // ceil(NN/32) buckets
#define GG 512    // scatter groups
#define EPB 3125  // edges per group = NE/GG
#define MAXB 3072 // max edges/bucket in LDS

typedef _Float16 half8 __attribute__((ext_vector_type(8)));
typedef _Float16 half2v __attribute__((ext_vector_type(2)));
typedef float floatx4 __attribute__((ext_vector_type(4)));

__device__ __forceinline__ float bf2f(unsigned short u) {
    union { unsigned int i; float f; } c;
    c.i = ((unsigned int)u) << 16;
    return c.f;
}
__device__ __forceinline__ float ldf(const void* p, size_t i, int f32) {
    return f32 ? ((const float*)p)[i] : bf2f(((const unsigned short*)p)[i]);
}

// ---------- dtype detectors: flags[0]=src int64, flags[1]=floats are fp32 ----------
__global__ void detect_kernel(const unsigned short* __restrict__ hv_u16,
                              const int* __restrict__ src, int* __restrict__ flags) {
    int i = threadIdx.x;  // 64 threads
    int garbage = 0;
    for (int k = 0; k < 4; k++) {
        unsigned short u = hv_u16[2 * (i * 4 + k)];
        int e = (u >> 7) & 0xFF;
        if (e >= 0x90 || (e <= 0x60 && (u & 0x7FFF) != 0)) garbage++;
    }
    unsigned long long gb = __ballot(garbage > 0);
    int odd = src[2 * i + 1];
    unsigned long long bal = __ballot(odd == 0);
    if (i == 0) {
        flags[1] = (__popcll(gb) >= 8) ? 1 : 0;
        flags[0] = (bal == 0xFFFFFFFFFFFFFFFFull) ? 1 : 0;
    }
}

// ---------- hi/lo split of a flag-dtype tensor ----------
__global__ void split_kernel(const void* __restrict__ in, _Float16* __restrict__ ph,
                             _Float16* __restrict__ pl, int n, const int* __restrict__ flags) {
    int i = blockIdx.x * blockDim.x + threadIdx.x;
    if (i >= n) return;
    float v = ldf(in, i, flags[1]);
    _Float16 h = (_Float16)v;
    ph[i] = h;
    pl[i] = (_Float16)(v - (float)h);
}

// ---------- fused 3-tensor bias convert ----------
__global__ void conv3_kernel(
    const void* __restrict__ i1, float* __restrict__ o1, int n1,
    const void* __restrict__ i2, float* __restrict__ o2, int n2,
    const void* __restrict__ i3, float* __restrict__ o3, int n3,
    const int* __restrict__ flags) {
    int i = blockIdx.x * blockDim.x + threadIdx.x;
    const void* in; float* out; int j = i;
    if (j < n1) { in = i1; out = o1; }
    else { j -= n1;
        if (j < n2) { in = i2; out = o2; }
        else { j -= n2; if (j >= n3) return; in = i3; out = o3; }
    }
    out[j] = ldf(in, j, flags[1]);
}

// ---------- Wc = Wih @ Wmsg (fp32), emitted directly as hi/lo f16 planes ----------
__global__ __launch_bounds__(256) void wc_kernel(
    const void* __restrict__ gWih, const void* __restrict__ msgW,
    _Float16* __restrict__ wcH, _Float16* __restrict__ wcL,
    const int* __restrict__ flags) {
    __shared__ float wrow[256];
    int tr = blockIdx.x;
    int t = tr / 384;
    int k = threadIdx.x;
    int f32 = flags[1];
    wrow[k] = ldf(gWih, (size_t)tr * 256 + k, f32);
    __syncthreads();
    float s = 0.f;
    size_t base = (size_t)t * 256 * 256;
    #pragma unroll 8
    for (int c = 0; c < 256; c++)
        s += wrow[c] * ldf(msgW, base + (size_t)c * 256 + k, f32);
    _Float16 h = (_Float16)s;
    wcH[(size_t)tr * 256 + k] = h;
    wcL[(size_t)tr * 256 + k] = (_Float16)(s - (float)h);
}

// ---------- c1 = Wih @ msg_b (fp32, per t) ----------
__global__ void c1_kernel(const void* __restrict__ gWih, const float* __restrict__ bMsg,
                          float* __restrict__ c1, const int* __restrict__ flags) {
    int tr = blockIdx.x * 64 + threadIdx.x;  // TT*384 total
    if (tr >= TT * 384) return;
    int t = tr / 384;
    int f32 = flags[1];
    float s = 0.f;
    for (int c = 0; c < 256; c++)
        s += ldf(gWih, (size_t)tr * 256 + c, f32) * bMsg[t * 256 + c];
    c1[tr] = s;
}

// ---------- Phase A: per-group bucket histograms (counts[g][b], coalesced) ----------
__global__ __launch_bounds__(256) void bucket_hist_kernel(const int* __restrict__ dst,
                                                          int* __restrict__ counts /*[GG][NB]*/) {
    __shared__ int h[NB];
    int g = blockIdx.x, tid = threadIdx.x;
    for (int b = tid; b < NB; b += 256) h[b] = 0;
    __syncthreads();
    int beg = g * EPB, end = min(NE, beg + EPB);
    for (int e = beg + tid; e < end; e += 256) atomicAdd(&h[dst[e] >> 5], 1);
    __syncthreads();
    for (int b = tid; b < NB; b += 256) counts[(size_t)g * NB + b] = h[b];
}

// ---------- bucket totals: sum over GG groups (8 strided loads + butterfly) ----------
__global__ __launch_bounds__(256) void bucket_sum_kernel(const int* __restrict__ counts,
                                                         int* __restrict__ bsum) {
    int b = blockIdx.x * 4 + (threadIdx.x >> 6);
    int lane = threadIdx.x & 63;
    if (b >= NB) return;
    int v = 0;
    #pragma unroll
    for (int j = 0; j < GG / 64; j++)
        v += counts[(size_t)(j * 64 + lane) * NB + b];
    #pragma unroll
    for (int off = 32; off > 0; off >>= 1) v += __shfl_down(v, off, 64);
    if (lane == 0) bsum[b] = v;
}

// ---------- exclusive scan of bsum -> bbase[0..NB] ----------
__global__ void bucket_scan_kernel(const int* __restrict__ bsum, int* __restrict__ bbase) {
    __shared__ int wsum[16];
    __shared__ int s_running;
    int tid = threadIdx.x, lane = tid & 63, w = tid >> 6;
    if (tid == 0) s_running = 0;
    __syncthreads();
    int nch = (NB + 1024) / 1024;  // 2
    for (int c = 0; c < nch; c++) {
        int idx = c * 1024 + tid;
        int v = (idx < NB) ? bsum[idx] : 0;
        int s = v;
        #pragma unroll
        for (int off = 1; off < 64; off <<= 1) {
            int t = __shfl_up(s, off, 64);
            if (lane >= off) s += t;
        }
        if (lane == 63) wsum[w] = s;
        __syncthreads();
        if (w == 0) {
            int ws = (lane < 16) ? wsum[lane] : 0;
            #pragma unroll
            for (int off = 1; off < 16; off <<= 1) {
                int t = __shfl_up(ws, off, 64);
                if (lane >= off) ws += t;
            }
            if (lane < 16) wsum[lane] = ws;
        }
        __syncthreads();
        int incl = s + ((w > 0) ? wsum[w - 1] : 0);
        int base = s_running;
        if (idx <= NB) bbase[idx] = base + incl - v;
        __syncthreads();
        if (tid == 1023) s_running = base + incl;
        __syncthreads();
    }
}

// ---------- per-(bucket,group) segment offsets: 8-chunk wave scan + carry ----------
__global__ __launch_bounds__(256) void bucket_offsets_kernel(const int* __restrict__ counts,
                                                             const int* __restrict__ bbase,
                                                             int* __restrict__ offsets) {
    int b = blockIdx.x * 4 + (threadIdx.x >> 6);
    int lane = threadIdx.x & 63;
    if (b >= NB) return;
    int carry = bbase[b];
    #pragma unroll
    for (int j = 0; j < GG / 64; j++) {
        int v = counts[(size_t)(j * 64 + lane) * NB + b];
        int s = v;
        #pragma unroll
        for (int off = 1; off < 64; off <<= 1) {
            int t = __shfl_up(s, off, 64);
            if (lane >= off) s += t;
        }
        offsets[(size_t)(j * 64 + lane) * NB + b] = carry + s - v;
        carry += __shfl(s, 63, 64);
    }
}

// ---------- Phase B: scatter packed edges (bucket-major); offsets[g][b] coalesced ----------
__global__ __launch_bounds__(256) void bucket_scatter_kernel(
    const int* __restrict__ src, const int* __restrict__ dst,
    const int* __restrict__ offsets, int* __restrict__ pairs,
    const int* __restrict__ flags) {
    __shared__ int ofs[NB];
    int g = blockIdx.x, tid = threadIdx.x;
    for (int b = tid; b < NB; b += 256) ofs[b] = offsets[(size_t)g * NB + b];
    __syncthreads();
    int beg = g * EPB, end = min(NE, beg + EPB);
    int f64 = flags[0];
    for (int e = beg + tid; e < end; e += 256) {
        int d = dst[e];
        int s = f64 ? src[2 * e] : src[e];
        int pos = atomicAdd(&ofs[d >> 5], 1);
        pairs[pos] = ((d & 31) << 16) | s;   // NN < 2^16
    }
}

// ---------- Phase C: in-bucket counting sort, per-wave counters (R23-proven) ----------
__global__ __launch_bounds__(256) void bucket_sort_kernel(
    const int* __restrict__ bbase, int* __restrict__ pairs,
    int* __restrict__ row, int* __restrict__ deg) {
    __shared__ int buf[MAXB];
    __shared__ int cnt[4][32];
    __shared__ int off[4][32];
    int b = blockIdx.x, tid = threadIdx.x;
    int w = tid >> 6;
    int beg = bbase[b], end = bbase[b + 1];
    int nE = end - beg;
    if (nE > MAXB) nE = MAXB;
    if (tid < 128) ((int*)cnt)[tid] = 0;
    __syncthreads();
    for (int i = tid; i < nE; i += 256) {
        int pk = pairs[beg + i];
        buf[i] = pk;
        atomicAdd(&cnt[w][pk >> 16], 1);
    }
    __syncthreads();
    if (tid < 32) {
        int k = tid;
        int c0 = cnt[0][k], c1 = cnt[1][k], c2 = cnt[2][k], c3 = cnt[3][k];
        int tot = c0 + c1 + c2 + c3;
        int s = tot;
        #pragma unroll
        for (int o = 1; o < 32; o <<= 1) {
            int t = __shfl_up(s, o, 64);
            if (k >= o) s += t;
        }
        int keyBase = beg + s - tot;   // absolute exclusive prefix
        off[0][k] = keyBase;
        off[1][k] = keyBase + c0;
        off[2][k] = keyBase + c0 + c1;
        off[3][k] = keyBase + c0 + c1 + c2;
        int gn = b * 32 + k;
        if (gn < NN) { row[gn] = keyBase; deg[gn] = tot; }
        if (k == 0 && b == NB - 1) row[NN] = end;
    }
    __syncthreads();
    if (tid < 128) ((int*)cnt)[tid] = ((int*)off)[tid];
    __syncthreads();
    for (int i = tid; i < nE; i += 256) {
        int pk = buf[i];
        int pos = atomicAdd(&cnt[w][pk >> 16], 1);   // absolute position
        pairs[pos] = pk & 0xFFFF;
    }
}

// ---------- per-node gather, 16-wide (R21-proven) ----------
__global__ __launch_bounds__(64) void gather_kernel(
    const int* __restrict__ row, const int* __restrict__ csr,
    const _Float16* __restrict__ hvH,
    _Float16* __restrict__ SH, _Float16* __restrict__ SL) {
    int n = blockIdx.x;
    int lane = threadIdx.x;
    const half2v* hv2 = (const half2v*)hvH;
    int beg = row[n], end = row[n + 1];
    float sx = 0.f, sy = 0.f;
    int e = beg;
    for (; e + 16 <= end; e += 16) {
        int s0 = csr[e],      s1 = csr[e + 1],  s2 = csr[e + 2],  s3 = csr[e + 3];
        int s4 = csr[e + 4],  s5 = csr[e + 5],  s6 = csr[e + 6],  s7 = csr[e + 7];
        int s8 = csr[e + 8],  s9 = csr[e + 9],  sA = csr[e + 10], sB = csr[e + 11];
        int sC = csr[e + 12], sD = csr[e + 13], sE = csr[e + 14], sF = csr[e + 15];
        half2v v0 = hv2[(size_t)s0 * 64 + lane];
        half2v v1 = hv2[(size_t)s1 * 64 + lane];
        half2v v2 = hv2[(size_t)s2 * 64 + lane];
        half2v v3 = hv2[(size_t)s3 * 64 + lane];
        half2v v4 = hv2[(size_t)s4 * 64 + lane];
        half2v v5 = hv2[(size_t)s5 * 64 + lane];
        half2v v6 = hv2[(size_t)s6 * 64 + lane];
        half2v v7 = hv2[(size_t)s7 * 64 + lane];
        half2v v8 = hv2[(size_t)s8 * 64 + lane];
        half2v v9 = hv2[(size_t)s9 * 64 + lane];
        half2v vA = hv2[(size_t)sA * 64 + lane];
        half2v vB = hv2[(size_t)sB * 64 + lane];
        half2v vC = hv2[(size_t)sC * 64 + lane];
        half2v vD = hv2[(size_t)sD * 64 + lane];
        half2v vE = hv2[(size_t)sE * 64 + lane];
        half2v vF = hv2[(size_t)sF * 64 + lane];
        sx += (float)v0.x + (float)v1.x + (float)v2.x + (float)v3.x
            + (float)v4.x + (float)v5.x + (float)v6.x + (float)v7.x;
        sy += (float)v0.y + (float)v1.y + (float)v2.y + (float)v3.y
            + (float)v4.y + (float)v5.y + (float)v6.y + (float)v7.y;
        sx += (float)v8.x + (float)v9.x + (float)vA.x + (float)vB.x
            + (float)vC.x + (float)vD.x + (float)vE.x + (float)vF.x;
        sy += (float)v8.y + (float)v9.y + (float)vA.y + (float)vB.y
            + (float)vC.y + (float)vD.y + (float)vE.y + (float)vF.y;
    }
    for (; e + 8 <= end; e += 8) {
        int s0 = csr[e], s1 = csr[e + 1], s2 = csr[e + 2], s3 = csr[e + 3];
        int s4 = csr[e + 4], s5 = csr[e + 5], s6 = csr[e + 6], s7 = csr[e + 7];
        half2v v0 = hv2[(size_t)s0 * 64 + lane];
        half2v v1 = hv2[(size_t)s1 * 64 + lane];
        half2v v2 = hv2[(size_t)s2 * 64 + lane];
        half2v v3 = hv2[(size_t)s3 * 64 + lane];
        half2v v4 = hv2[(size_t)s4 * 64 + lane];
        half2v v5 = hv2[(size_t)s5 * 64 + lane];
        half2v v6 = hv2[(size_t)s6 * 64 + lane];
        half2v v7 = hv2[(size_t)s7 * 64 + lane];
        sx += (float)v0.x + (float)v1.x + (float)v2.x + (float)v3.x
            + (float)v4.x + (float)v5.x + (float)v6.x + (float)v7.x;
        sy += (float)v0.y + (float)v1.y + (float)v2.y + (float)v3.y
            + (float)v4.y + (float)v5.y + (float)v6.y + (float)v7.y;
    }
    for (; e < end; e++) {
        half2v v = hv2[(size_t)csr[e] * 64 + lane];
        sx += (float)v.x; sy += (float)v.y;
    }
    half2v hx, lx;
    hx.x = (_Float16)sx; lx.x = (_Float16)(sx - (float)hx.x);
    hx.y = (_Float16)sy; lx.y = (_Float16)(sy - (float)hx.y);
    ((half2v*)SH)[(size_t)n * 64 + lane] = hx;
    ((half2v*)SL)[(size_t)n * 64 + lane] = lx;
}

// ---------- shared GEMM body (R23-proven math, NT=8, 128-row n-tile) ----------
// MODE0 (gi, KK=256): stage W[:,0:128] -> k-loop (A=hv) -> acc *= deg ->
// stage W[:,128:256] -> k-loop (A=S) accumulates same acc; epilogue adds
// bias + deg*bias2.  MODE1 (gh, KK=128): single stage, A = AhB/AlB (=hv).
// split precision: acc += Ah*Wh + Al*Wh + Ah*Wl  (R4-R17 verified).
// MFMA frag map (R4-R10 verified): A row = m0+wm+mt*16+lr, k = k0+quad*8;
//   B row = LDS row nt*16+lr, k = k0+quad*8; D col = lane&15, row = quad*4+reg.
template<int KK, int MODE>
__device__ __forceinline__ void gemm_body(
    _Float16 (*Wsh)[136], _Float16 (*Wsl)[136],
    const _Float16* __restrict__ AhA, const _Float16* __restrict__ AlA,
    const _Float16* __restrict__ AhB, const _Float16* __restrict__ AlB,
    const _Float16* __restrict__ Wh,  const _Float16* __restrict__ Wl,
    const float* __restrict__ bias, const float* __restrict__ bias2,
    _Float16* __restrict__ outC, const int* __restrict__ deg, int M, int sub) {
    constexpr int KH  = 128;
    constexpr int NST = KK / KH;   // 2 (gi) or 1 (gh)
    constexpr int NT  = 8;
    constexpr int NROWS = 128;
    constexpr int NTILES = 3;      // 384 / 128
    int n0 = (sub % NTILES) * NROWS;
    int m0 = (sub / NTILES) * 128;

    int tid = threadIdx.x;
    int wave = tid >> 6, lane = tid & 63;
    int lr = lane & 15, quad = lane >> 4;
    int wm = wave * 32;

    int gm[2]; bool vm[2];
    #pragma unroll
    for (int mt = 0; mt < 2; mt++) { gm[mt] = m0 + wm + mt * 16 + lr; vm[mt] = gm[mt] < M; }

    float dvr[2][4];
    #pragma unroll
    for (int mt = 0; mt < 2; mt++)
        #pragma unroll
        for (int rg = 0; rg < 4; rg++) {
            int m = m0 + wm + mt * 16 + quad * 4 + rg;
            dvr[mt][rg] = (MODE == 0 && m < M) ? (float)deg[m] : 0.f;
        }

    floatx4 acc[2][NT] = {};

    int srr = tid >> 4;
    int scc = (tid & 15) * 8;

    #pragma unroll
    for (int s = 0; s < NST; s++) {
        if (s > 0) __syncthreads();
        #pragma unroll
        for (int base = 0; base < NROWS; base += 16) {
            int rw = base + srr;
            *(half8*)&Wsh[rw][scc] =
                *(const half8*)(Wh + (size_t)(n0 + rw) * KK + s * KH + scc);
            *(half8*)&Wsl[rw][scc] =
                *(const half8*)(Wl + (size_t)(n0 + rw) * KK + s * KH + scc);
        }
        __syncthreads();

        const bool leftStage = (MODE == 0) && (s == 0);
        const _Float16* Ph = leftStage ? AhA : AhB;
        const _Float16* Pl = leftStage ? AlA : AlB;

        #pragma unroll
        for (int k0 = 0; k0 < KH; k0 += 32) {
            int kk = k0 + quad * 8;
            half8 afh[2] = {}, afl[2] = {};
            #pragma unroll
            for (int mt = 0; mt < 2; mt++) if (vm[mt]) {
                afh[mt] = *(const half8*)(Ph + (size_t)gm[mt] * HH + kk);
                afl[mt] = *(const half8*)(Pl + (size_t)gm[mt] * HH + kk);
            }
            #pragma unroll
            for (int nt = 0; nt < NT; nt++) {
                half8 bh = *(const half8*)&Wsh[nt * 16 + lr][kk];
                half8 bl = *(const half8*)&Wsl[nt * 16 + lr][kk];
                #pragma unroll
                for (int mt = 0; mt < 2; mt++) {
                    acc[mt][nt] = __builtin_amdgcn_mfma_f32_16x16x32_f16(afh[mt], bh, acc[mt][nt], 0, 0, 0);
                    acc[mt][nt] = __builtin_amdgcn_mfma_f32_16x16x32_f16(afl[mt], bh, acc[mt][nt], 0, 0, 0);
                    acc[mt][nt] = __builtin_amdgcn_mfma_f32_16x16x32_f16(afh[mt], bl, acc[mt][nt], 0, 0, 0);
                }
            }
        }

        if (leftStage) {
            #pragma unroll
            for (int mt = 0; mt < 2; mt++)
                #pragma unroll
                for (int nt = 0; nt < NT; nt++)
                    #pragma unroll
                    for (int rg = 0; rg < 4; rg++)
                        acc[mt][nt][rg] *= dvr[mt][rg];
        }
    }

    #pragma unroll
    for (int mt = 0; mt < 2; mt++) {
        #pragma unroll
        for (int rg = 0; rg < 4; rg++) {
            int m = m0 + wm + mt * 16 + quad * 4 + rg;
            if (m >= M) continue;
            #pragma unroll
            for (int nt = 0; nt < NT; nt++) {
                int n = n0 + nt * 16 + lr;
                float v = acc[mt][nt][rg] + bias[n];
                if (MODE == 0) v += dvr[mt][rg] * bias2[n];
                outC[(size_t)m * 384 + n] = (_Float16)v;
            }
        }
    }
}

__device__ __forceinline__ int swz_wid(int bid, int nwg) {
    int q = nwg >> 3, r = nwg & 7;
    int xcd = bid & 7, pos = bid >> 3;
    return (xcd < r ? xcd * (q + 1) : r * (q + 1) + (xcd - r) * q) + pos;
}

// ---------- serial-mode GEMM kernels (R23 fallback) ----------
template<int KK, int MODE>
__global__ __launch_bounds__(256) void gemm_t(
    const _Float16* __restrict__ AhA, const _Float16* __restrict__ AlA,
    const _Float16* __restrict__ AhB, const _Float16* __restrict__ AlB,
    const _Float16* __restrict__ Wh,  const _Float16* __restrict__ Wl,
    const float* __restrict__ bias, const float* __restrict__ bias2,
    _Float16* __restrict__ outC, const int* __restrict__ deg, int M) {
    __shared__ _Float16 Wsh[128][136];
    __shared__ _Float16 Wsl[128][136];
    int wid = swz_wid(blockIdx.x, gridDim.x);
    gemm_body<KK, MODE>(Wsh, Wsl, AhA, AlA, AhB, AlB, Wh, Wl,
                        bias, bias2, outC, deg, M, wid);
}

// ---------- R24 merged gi+gh kernel (mode = wid&1, sub = wid>>1) ----------
__global__ __launch_bounds__(256) void gemm_fused(
    const _Float16* __restrict__ hvH, const _Float16* __restrict__ hvL,
    const _Float16* __restrict__ SH, const _Float16* __restrict__ SL,
    const _Float16* __restrict__ WcH, const _Float16* __restrict__ WcL,
    const _Float16* __restrict__ WhH, const _Float16* __restrict__ WhL,
    const float* __restrict__ bIh, const float* __restrict__ c1v,
    const float* __restrict__ bHh,
    _Float16* __restrict__ gi, _Float16* __restrict__ gh,
    const int* __restrict__ deg, int M) {
    __shared__ _Float16 Wsh[128][136];
    __shared__ _Float16 Wsl[128][136];
    int wid = swz_wid(blockIdx.x, gridDim.x);
    int sub = wid >> 1;
    if ((wid & 1) == 0)
        gemm_body<256, 0>(Wsh, Wsl, hvH, hvL, SH, SL, WcH, WcL,
                          bIh, c1v, gi, deg, M, sub);
    else
        gemm_body<128, 1>(Wsh, Wsl, hvH, hvL, hvH, hvL, WhH, WhL,
                          bHh, nullptr, gh, deg, M, sub);
}

// ---------- fused GRU gates, half8-vectorized (R21-proven) ----------
__global__ void gate_kernel(const _Float16* __restrict__ gi,
                            const _Float16* __restrict__ gh,
                            _Float16* __restrict__ hvH, _Float16* __restrict__ hvL,
                            void* __restrict__ outv,
                            const int* __restrict__ flags, int writeOut, int total8) {
    int idx = blockIdx.x * blockDim.x + threadIdx.x;   // one thread per 8 cols
    if (idx >= total8) return;
    int n = idx >> 4;          // HH/8 = 16 chunks per node
    int jv = (idx & 15) * 8;   // column base within row
    size_t base = (size_t)n * 384 + jv;
    half8 ir  = *(const half8*)(gi + base);
    half8 iz  = *(const half8*)(gi + base + 128);
    half8 inn = *(const half8*)(gi + base + 256);
    half8 hr  = *(const half8*)(gh + base);
    half8 hz  = *(const half8*)(gh + base + 128);
    half8 hnn = *(const half8*)(gh + base + 256);
    size_t hbase = (size_t)n * HH + jv;
    half8 hH = *(const half8*)(hvH + hbase);
    half8 hL = *(const half8*)(hvL + hbase);
    half8 oH, oL;
    float outf[8];
    #pragma unroll
    for (int qv = 0; qv < 8; qv++) {
        float i_r = (float)ir[qv], i_z = (float)iz[qv], i_n = (float)inn[qv];
        float h_r = (float)hr[qv], h_z = (float)hz[qv], h_n = (float)hnn[qv];
        float h = (float)hH[qv] + (float)hL[qv];
        float r = 1.f / (1.f + __expf(-(i_r + h_r)));
        float z = 1.f / (1.f + __expf(-(i_z + h_z)));
        float nn = tanhf(i_n + r * h_n);
        float hn = (1.f - z) * nn + z * h;
        _Float16 hh = (_Float16)hn;
        oH[qv] = hh;
        oL[qv] = (_Float16)(hn - (float)hh);
        outf[qv] = hn;
    }
    *(half8*)(hvH + hbase) = oH;
    *(half8*)(hvL + hbase) = oL;
    if (writeOut) {
        if (flags[1]) {
            float* op = (float*)outv + hbase;
            #pragma unroll
            for (int qv = 0; qv < 8; qv++) op[qv] = outf[qv];
        } else {
            __hip_bfloat16* op = (__hip_bfloat16*)outv + hbase;
            #pragma unroll
            for (int qv = 0; qv < 8; qv++) op[qv] = __float2bfloat16(outf[qv]);
        }
    }
}

extern "C" void kernel_launch(void* const* d_in, const int* in_sizes, int n_in,
                              void* d_out, int out_size, void* d_ws, size_t ws_size,
                              hipStream_t stream) {
    const void* hv_in   = d_in[0];
    const int* edge_src = (const int*)d_in[1];
    const int* edge_dst = (const int*)d_in[2];
    const void* msg_W = d_in[3];
    const void* msg_b = d_in[4];
    const void* gWih  = d_in[5];
    const void* gWhh  = d_in[6];
    const void* gbih  = d_in[7];
    const void* gbhh  = d_in[8];

    // ---- workspace carve-up ----
    char* p = (char*)d_ws;
    auto alloc = [&](size_t bytes) -> void* {
        void* r = (void*)p;
        p += (bytes + 255) & ~(size_t)255;
        return r;
    };
    int* flags   = (int*)alloc(256);
    int* deg     = (int*)alloc((size_t)NN * 4);
    int* row     = (int*)alloc((size_t)(NN + 1) * 4);
    int* counts  = (int*)alloc((size_t)GG * NB * 4);   // 3.2 MB, [g][b]
    int* bsum    = (int*)alloc((size_t)NB * 4);
    int* bbase   = (int*)alloc((size_t)(NB + 1) * 4);
    int* offsets = (int*)alloc((size_t)GG * NB * 4);   // 3.2 MB, [g][b]
    int* pairs   = (int*)alloc((size_t)NE * 4);        // becomes sorted csr
    _Float16* wCcH = (_Float16*)alloc((size_t)TT * 384 * 256 * 2);  // Wc hi
    _Float16* wCcL = (_Float16*)alloc((size_t)TT * 384 * 256 * 2);  // Wc lo
    _Float16* wHhH = (_Float16*)alloc((size_t)TT * 384 * 128 * 2);
    _Float16* wHhL = (_Float16*)alloc((size_t)TT * 384 * 128 * 2);
    float* bMsg = (float*)alloc((size_t)TT * 256 * 4);
    float* bIh  = (float*)alloc((size_t)TT * 384 * 4);
    float* bHh  = (float*)alloc((size_t)TT * 384 * 4);
    float* c1   = (float*)alloc((size_t)TT * 384 * 4);
    _Float16* hvH = (_Float16*)alloc((size_t)NN * HH * 2);   // 12.8 MB
    _Float16* hvL = (_Float16*)alloc((size_t)NN * HH * 2);   // 12.8 MB

    size_t used = (size_t)(p - (char*)d_ws);
    const size_t planeS  = (size_t)NN * HH * 2;   // 12.8 MB
    const size_t planeG  = (size_t)NN * 384 * 2;  // 38.4 MB
    // merged needs: SH + SL + gi + gh; serial needs: PA + PB (S/gh aliased)
    size_t needMerged = used + 2 * (planeS + 256) + 2 * (planeG + 256);
    bool merged = (needMerged <= ws_size);

    _Float16 *SH, *SL, *gi, *gh;
    if (merged) {
        SH = (_Float16*)alloc(planeS);
        SL = (_Float16*)alloc(planeS);
        gi = (_Float16*)alloc(planeG);
        gh = (_Float16*)alloc(planeG);
    } else {
        char* PA = (char*)alloc(planeG);
        char* PB = (char*)alloc(planeG);
        gi = (_Float16*)PA;
        SH = (_Float16*)PB;
        SL = (_Float16*)(PB + planeS);
        gh = (_Float16*)PB;   // overwrites dead S after gi-GEMM (serial only)
    }
    (void)ws_size; (void)in_sizes; (void)n_in; (void)out_size;

    // ---- dtype detection + preprocessing ----
    detect_kernel<<<1, 64, 0, stream>>>((const unsigned short*)hv_in, edge_src, flags);
    split_kernel<<<(NN * HH + 255) / 256, 256, 0, stream>>>(hv_in, hvH, hvL, NN * HH, flags);
    split_kernel<<<(TT * 384 * 128 + 255) / 256, 256, 0, stream>>>(
        gWhh, wHhH, wHhL, TT * 384 * 128, flags);
    {
        int n1 = TT * 256, n2 = TT * 384, n3 = TT * 384;
        conv3_kernel<<<(n1 + n2 + n3 + 255) / 256, 256, 0, stream>>>(
            msg_b, bMsg, n1, gbih, bIh, n2, gbhh, bHh, n3, flags);
    }
    wc_kernel<<<TT * 384, 256, 0, stream>>>(gWih, msg_W, wCcH, wCcL, flags);
    c1_kernel<<<(TT * 384 + 63) / 64, 64, 0, stream>>>(gWih, bMsg, c1, flags);

    // ---- bucket-CSR build + in-bucket sort -> per-node CSR ----
    bucket_hist_kernel<<<GG, 256, 0, stream>>>(edge_dst, counts);
    bucket_sum_kernel<<<(NB + 3) / 4, 256, 0, stream>>>(counts, bsum);
    bucket_scan_kernel<<<1, 1024, 0, stream>>>(bsum, bbase);
    bucket_offsets_kernel<<<(NB + 3) / 4, 256, 0, stream>>>(counts, bbase, offsets);
    bucket_scatter_kernel<<<GG, 256, 0, stream>>>(edge_src, edge_dst, offsets, pairs, flags);
    bucket_sort_kernel<<<NB, 256, 0, stream>>>(bbase, pairs, row, deg);

    const int mt128 = (NN + 127) / 128;   // 391 m-tiles

    for (int t = 0; t < TT; t++) {
        // S planes from per-node 16-wide gather
        gather_kernel<<<NN, 64, 0, stream>>>(row, pairs, hvH, SH, SL);

        if (merged) {
            // gi + gh in ONE dispatch: 2346 blocks, mode = wid&1.
            gemm_fused<<<mt128 * 6, 256, 0, stream>>>(
                hvH, hvL, SH, SL,
                wCcH + (size_t)t * 384 * 256, wCcL + (size_t)t * 384 * 256,
                wHhH + (size_t)t * 384 * 128, wHhL + (size_t)t * 384 * 128,
                bIh + (size_t)t * 384, c1 + (size_t)t * 384, bHh + (size_t)t * 384,
                gi, gh, deg, NN);
        } else {
            // R23 serial fallback (gh aliases dead S)
            gemm_t<256, 0><<<mt128 * 3, 256, 0, stream>>>(
                hvH, hvL, SH, SL,
                wCcH + (size_t)t * 384 * 256, wCcL + (size_t)t * 384 * 256,
                bIh + (size_t)t * 384, c1 + (size_t)t * 384, gi, deg, NN);
            gemm_t<128, 1><<<mt128 * 3, 256, 0, stream>>>(
                hvH, hvL, hvH, hvL,
                wHhH + (size_t)t * 384 * 128, wHhL + (size_t)t * 384 * 128,
                bHh + (size_t)t * 384, nullptr, gh, deg, NN);
        }

        // GRU gates (half8-vectorized); dtype-aware output on last round
        gate_kernel<<<(NN * 16 + 255) / 256, 256, 0, stream>>>(
            gi, gh, hvH, hvL, d_out, flags, (t == TT - 1) ? 1 : 0, NN * 16);
    }
}

// Round 16
// 485.400 us; speedup vs baseline: 1.0437x; 1.0437x over previous
//
#include <hip/hip_runtime.h>
#include <hip/hip_bf16.h>

// GraphProp R25: REVERT to R23 (best measured: 488us). R24's gi+gh merge
// fired its falsifier (merged 89.7us > serial 79us: per-CU co-residency of
// gi+gh blocks doubles the L2 working set (Wc+Whh+hv+S) and interleaved
// LDS phases raised bank conflicts 2.4M->3.6M). Refuted; reverted.
// Final configuration (each piece bench-proven):
//  - gi-GEMM: NT=8, half-K staged LDS (69.6KB), in-place f32 deg rescale
//    (R20; converged 51-65us across sessions, MfmaUtil ~21%).
//  - gh-GEMM: NT=8 same shape (R23).
//  - graph build: GG=512 groups, group-major counts/offsets (R22);
//    per-wave-counter bucket sort (R23); in-LDS bucket CSR (R8).
//  - gather 16-wide (R21), gate half8-vectorized (R21), wc unroll 8 (R21).
//  - split-precision f16 hi/lo planes throughout (R4-R17 verified).
// Refuted dead-ends (do not revisit): round-fusion (R12/R18, VGPR 184-220);
// inner-loop global W (R14/R16); preload-all (R15); persistent blocks
// (R19); launch_bounds VGPR caps (R14); gi+gh merge (R24).

#define NN 50000
#define NE 1600000
#define HH 128
#define TT 2
#define NB 1563   // ceil(NN/32) buckets
#define GG 512    // scatter groups
#define EPB 3125  // edges per group = NE/GG
#define MAXB 3072 // max edges/bucket in LDS

typedef _Float16 half8 __attribute__((ext_vector_type(8)));
typedef _Float16 half2v __attribute__((ext_vector_type(2)));
typedef float floatx4 __attribute__((ext_vector_type(4)));

__device__ __forceinline__ float bf2f(unsigned short u) {
    union { unsigned int i; float f; } c;
    c.i = ((unsigned int)u) << 16;
    return c.f;
}
__device__ __forceinline__ float ldf(const void* p, size_t i, int f32) {
    return f32 ? ((const float*)p)[i] : bf2f(((const unsigned short*)p)[i]);
}

// ---------- dtype detectors: flags[0]=src int64, flags[1]=floats are fp32 ----------
__global__ void detect_kernel(const unsigned short* __restrict__ hv_u16,
                              const int* __restrict__ src, int* __restrict__ flags) {
    int i = threadIdx.x;  // 64 threads
    int garbage = 0;
    for (int k = 0; k < 4; k++) {
        unsigned short u = hv_u16[2 * (i * 4 + k)];
        int e = (u >> 7) & 0xFF;
        if (e >= 0x90 || (e <= 0x60 && (u & 0x7FFF) != 0)) garbage++;
    }
    unsigned long long gb = __ballot(garbage > 0);
    int odd = src[2 * i + 1];
    unsigned long long bal = __ballot(odd == 0);
    if (i == 0) {
        flags[1] = (__popcll(gb) >= 8) ? 1 : 0;
        flags[0] = (bal == 0xFFFFFFFFFFFFFFFFull) ? 1 : 0;
    }
}

// ---------- hi/lo split of a flag-dtype tensor ----------
__global__ void split_kernel(const void* __restrict__ in, _Float16* __restrict__ ph,
                             _Float16* __restrict__ pl, int n, const int* __restrict__ flags) {
    int i = blockIdx.x * blockDim.x + threadIdx.x;
    if (i >= n) return;
    float v = ldf(in, i, flags[1]);
    _Float16 h = (_Float16)v;
    ph[i] = h;
    pl[i] = (_Float16)(v - (float)h);
}

// ---------- fused 3-tensor bias convert ----------
__global__ void conv3_kernel(
    const void* __restrict__ i1, float* __restrict__ o1, int n1,
    const void* __restrict__ i2, float* __restrict__ o2, int n2,
    const void* __restrict__ i3, float* __restrict__ o3, int n3,
    const int* __restrict__ flags) {
    int i = blockIdx.x * blockDim.x + threadIdx.x;
    const void* in; float* out; int j = i;
    if (j < n1) { in = i1; out = o1; }
    else { j -= n1;
        if (j < n2) { in = i2; out = o2; }
        else { j -= n2; if (j >= n3) return; in = i3; out = o3; }
    }
    out[j] = ldf(in, j, flags[1]);
}

// ---------- Wc = Wih @ Wmsg (fp32), emitted directly as hi/lo f16 planes ----------
__global__ __launch_bounds__(256) void wc_kernel(
    const void* __restrict__ gWih, const void* __restrict__ msgW,
    _Float16* __restrict__ wcH, _Float16* __restrict__ wcL,
    const int* __restrict__ flags) {
    __shared__ float wrow[256];
    int tr = blockIdx.x;
    int t = tr / 384;
    int k = threadIdx.x;
    int f32 = flags[1];
    wrow[k] = ldf(gWih, (size_t)tr * 256 + k, f32);
    __syncthreads();
    float s = 0.f;
    size_t base = (size_t)t * 256 * 256;
    #pragma unroll 8
    for (int c = 0; c < 256; c++)
        s += wrow[c] * ldf(msgW, base + (size_t)c * 256 + k, f32);
    _Float16 h = (_Float16)s;
    wcH[(size_t)tr * 256 + k] = h;
    wcL[(size_t)tr * 256 + k] = (_Float16)(s - (float)h);
}

// ---------- c1 = Wih @ msg_b (fp32, per t) ----------
__global__ void c1_kernel(const void* __restrict__ gWih, const float* __restrict__ bMsg,
                          float* __restrict__ c1, const int* __restrict__ flags) {
    int tr = blockIdx.x * 64 + threadIdx.x;  // TT*384 total
    if (tr >= TT * 384) return;
    int t = tr / 384;
    int f32 = flags[1];
    float s = 0.f;
    for (int c = 0; c < 256; c++)
        s += ldf(gWih, (size_t)tr * 256 + c, f32) * bMsg[t * 256 + c];
    c1[tr] = s;
}

// ---------- Phase A: per-group bucket histograms (counts[g][b], coalesced) ----------
__global__ __launch_bounds__(256) void bucket_hist_kernel(const int* __restrict__ dst,
                                                          int* __restrict__ counts /*[GG][NB]*/) {
    __shared__ int h[NB];
    int g = blockIdx.x, tid = threadIdx.x;
    for (int b = tid; b < NB; b += 256) h[b] = 0;
    __syncthreads();
    int beg = g * EPB, end = min(NE, beg + EPB);
    for (int e = beg + tid; e < end; e += 256) atomicAdd(&h[dst[e] >> 5], 1);
    __syncthreads();
    for (int b = tid; b < NB; b += 256) counts[(size_t)g * NB + b] = h[b];
}

// ---------- bucket totals: sum over GG groups (8 strided loads + butterfly) ----------
__global__ __launch_bounds__(256) void bucket_sum_kernel(const int* __restrict__ counts,
                                                         int* __restrict__ bsum) {
    int b = blockIdx.x * 4 + (threadIdx.x >> 6);
    int lane = threadIdx.x & 63;
    if (b >= NB) return;
    int v = 0;
    #pragma unroll
    for (int j = 0; j < GG / 64; j++)
        v += counts[(size_t)(j * 64 + lane) * NB + b];
    #pragma unroll
    for (int off = 32; off > 0; off >>= 1) v += __shfl_down(v, off, 64);
    if (lane == 0) bsum[b] = v;
}

// ---------- exclusive scan of bsum -> bbase[0..NB] ----------
__global__ void bucket_scan_kernel(const int* __restrict__ bsum, int* __restrict__ bbase) {
    __shared__ int wsum[16];
    __shared__ int s_running;
    int tid = threadIdx.x, lane = tid & 63, w = tid >> 6;
    if (tid == 0) s_running = 0;
    __syncthreads();
    int nch = (NB + 1024) / 1024;  // 2
    for (int c = 0; c < nch; c++) {
        int idx = c * 1024 + tid;
        int v = (idx < NB) ? bsum[idx] : 0;
        int s = v;
        #pragma unroll
        for (int off = 1; off < 64; off <<= 1) {
            int t = __shfl_up(s, off, 64);
            if (lane >= off) s += t;
        }
        if (lane == 63) wsum[w] = s;
        __syncthreads();
        if (w == 0) {
            int ws = (lane < 16) ? wsum[lane] : 0;
            #pragma unroll
            for (int off = 1; off < 16; off <<= 1) {
                int t = __shfl_up(ws, off, 64);
                if (lane >= off) ws += t;
            }
            if (lane < 16) wsum[lane] = ws;
        }
        __syncthreads();
        int incl = s + ((w > 0) ? wsum[w - 1] : 0);
        int base = s_running;
        if (idx <= NB) bbase[idx] = base + incl - v;
        __syncthreads();
        if (tid == 1023) s_running = base + incl;
        __syncthreads();
    }
}

// ---------- per-(bucket,group) segment offsets: 8-chunk wave scan + carry ----------
__global__ __launch_bounds__(256) void bucket_offsets_kernel(const int* __restrict__ counts,
                                                             const int* __restrict__ bbase,
                                                             int* __restrict__ offsets) {
    int b = blockIdx.x * 4 + (threadIdx.x >> 6);
    int lane = threadIdx.x & 63;
    if (b >= NB) return;
    int carry = bbase[b];
    #pragma unroll
    for (int j = 0; j < GG / 64; j++) {
        int v = counts[(size_t)(j * 64 + lane) * NB + b];
        int s = v;
        #pragma unroll
        for (int off = 1; off < 64; off <<= 1) {
            int t = __shfl_up(s, off, 64);
            if (lane >= off) s += t;
        }
        offsets[(size_t)(j * 64 + lane) * NB + b] = carry + s - v;
        carry += __shfl(s, 63, 64);
    }
}

// ---------- Phase B: scatter packed edges (bucket-major); offsets[g][b] coalesced ----------
__global__ __launch_bounds__(256) void bucket_scatter_kernel(
    const int* __restrict__ src, const int* __restrict__ dst,
    const int* __restrict__ offsets, int* __restrict__ pairs,
    const int* __restrict__ flags) {
    __shared__ int ofs[NB];
    int g = blockIdx.x, tid = threadIdx.x;
    for (int b = tid; b < NB; b += 256) ofs[b] = offsets[(size_t)g * NB + b];
    __syncthreads();
    int beg = g * EPB, end = min(NE, beg + EPB);
    int f64 = flags[0];
    for (int e = beg + tid; e < end; e += 256) {
        int d = dst[e];
        int s = f64 ? src[2 * e] : src[e];
        int pos = atomicAdd(&ofs[d >> 5], 1);
        pairs[pos] = ((d & 31) << 16) | s;   // NN < 2^16
    }
}

// ---------- Phase C: in-bucket counting sort, per-wave counters (R23-proven) ----------
__global__ __launch_bounds__(256) void bucket_sort_kernel(
    const int* __restrict__ bbase, int* __restrict__ pairs,
    int* __restrict__ row, int* __restrict__ deg) {
    __shared__ int buf[MAXB];
    __shared__ int cnt[4][32];
    __shared__ int off[4][32];
    int b = blockIdx.x, tid = threadIdx.x;
    int w = tid >> 6;
    int beg = bbase[b], end = bbase[b + 1];
    int nE = end - beg;
    if (nE > MAXB) nE = MAXB;
    if (tid < 128) ((int*)cnt)[tid] = 0;
    __syncthreads();
    for (int i = tid; i < nE; i += 256) {
        int pk = pairs[beg + i];
        buf[i] = pk;
        atomicAdd(&cnt[w][pk >> 16], 1);
    }
    __syncthreads();
    if (tid < 32) {
        int k = tid;
        int c0 = cnt[0][k], c1 = cnt[1][k], c2 = cnt[2][k], c3 = cnt[3][k];
        int tot = c0 + c1 + c2 + c3;
        int s = tot;
        #pragma unroll
        for (int o = 1; o < 32; o <<= 1) {
            int t = __shfl_up(s, o, 64);
            if (k >= o) s += t;
        }
        int keyBase = beg + s - tot;   // absolute exclusive prefix
        off[0][k] = keyBase;
        off[1][k] = keyBase + c0;
        off[2][k] = keyBase + c0 + c1;
        off[3][k] = keyBase + c0 + c1 + c2;
        int gn = b * 32 + k;
        if (gn < NN) { row[gn] = keyBase; deg[gn] = tot; }
        if (k == 0 && b == NB - 1) row[NN] = end;
    }
    __syncthreads();
    if (tid < 128) ((int*)cnt)[tid] = ((int*)off)[tid];
    __syncthreads();
    for (int i = tid; i < nE; i += 256) {
        int pk = buf[i];
        int pos = atomicAdd(&cnt[w][pk >> 16], 1);   // absolute position
        pairs[pos] = pk & 0xFFFF;
    }
}

// ---------- per-node gather, 16-wide (R21-proven) ----------
__global__ __launch_bounds__(64) void gather_kernel(
    const int* __restrict__ row, const int* __restrict__ csr,
    const _Float16* __restrict__ hvH,
    _Float16* __restrict__ SH, _Float16* __restrict__ SL) {
    int n = blockIdx.x;
    int lane = threadIdx.x;
    const half2v* hv2 = (const half2v*)hvH;
    int beg = row[n], end = row[n + 1];
    float sx = 0.f, sy = 0.f;
    int e = beg;
    for (; e + 16 <= end; e += 16) {
        int s0 = csr[e],      s1 = csr[e + 1],  s2 = csr[e + 2],  s3 = csr[e + 3];
        int s4 = csr[e + 4],  s5 = csr[e + 5],  s6 = csr[e + 6],  s7 = csr[e + 7];
        int s8 = csr[e + 8],  s9 = csr[e + 9],  sA = csr[e + 10], sB = csr[e + 11];
        int sC = csr[e + 12], sD = csr[e + 13], sE = csr[e + 14], sF = csr[e + 15];
        half2v v0 = hv2[(size_t)s0 * 64 + lane];
        half2v v1 = hv2[(size_t)s1 * 64 + lane];
        half2v v2 = hv2[(size_t)s2 * 64 + lane];
        half2v v3 = hv2[(size_t)s3 * 64 + lane];
        half2v v4 = hv2[(size_t)s4 * 64 + lane];
        half2v v5 = hv2[(size_t)s5 * 64 + lane];
        half2v v6 = hv2[(size_t)s6 * 64 + lane];
        half2v v7 = hv2[(size_t)s7 * 64 + lane];
        half2v v8 = hv2[(size_t)s8 * 64 + lane];
        half2v v9 = hv2[(size_t)s9 * 64 + lane];
        half2v vA = hv2[(size_t)sA * 64 + lane];
        half2v vB = hv2[(size_t)sB * 64 + lane];
        half2v vC = hv2[(size_t)sC * 64 + lane];
        half2v vD = hv2[(size_t)sD * 64 + lane];
        half2v vE = hv2[(size_t)sE * 64 + lane];
        half2v vF = hv2[(size_t)sF * 64 + lane];
        sx += (float)v0.x + (float)v1.x + (float)v2.x + (float)v3.x
            + (float)v4.x + (float)v5.x + (float)v6.x + (float)v7.x;
        sy += (float)v0.y + (float)v1.y + (float)v2.y + (float)v3.y
            + (float)v4.y + (float)v5.y + (float)v6.y + (float)v7.y;
        sx += (float)v8.x + (float)v9.x + (float)vA.x + (float)vB.x
            + (float)vC.x + (float)vD.x + (float)vE.x + (float)vF.x;
        sy += (float)v8.y + (float)v9.y + (float)vA.y + (float)vB.y
            + (float)vC.y + (float)vD.y + (float)vE.y + (float)vF.y;
    }
    for (; e + 8 <= end; e += 8) {
        int s0 = csr[e], s1 = csr[e + 1], s2 = csr[e + 2], s3 = csr[e + 3];
        int s4 = csr[e + 4], s5 = csr[e + 5], s6 = csr[e + 6], s7 = csr[e + 7];
        half2v v0 = hv2[(size_t)s0 * 64 + lane];
        half2v v1 = hv2[(size_t)s1 * 64 + lane];
        half2v v2 = hv2[(size_t)s2 * 64 + lane];
        half2v v3 = hv2[(size_t)s3 * 64 + lane];
        half2v v4 = hv2[(size_t)s4 * 64 + lane];
        half2v v5 = hv2[(size_t)s5 * 64 + lane];
        half2v v6 = hv2[(size_t)s6 * 64 + lane];
        half2v v7 = hv2[(size_t)s7 * 64 + lane];
        sx += (float)v0.x + (float)v1.x + (float)v2.x + (float)v3.x
            + (float)v4.x + (float)v5.x + (float)v6.x + (float)v7.x;
        sy += (float)v0.y + (float)v1.y + (float)v2.y + (float)v3.y
            + (float)v4.y + (float)v5.y + (float)v6.y + (float)v7.y;
    }
    for (; e < end; e++) {
        half2v v = hv2[(size_t)csr[e] * 64 + lane];
        sx += (float)v.x; sy += (float)v.y;
    }
    half2v hx, lx;
    hx.x = (_Float16)sx; lx.x = (_Float16)(sx - (float)hx.x);
    hx.y = (_Float16)sy; lx.y = (_Float16)(sy - (float)hx.y);
    ((half2v*)SH)[(size_t)n * 64 + lane] = hx;
    ((half2v*)SL)[(size_t)n * 64 + lane] = lx;
}

// ---------- GEMM: half-K staged LDS, NT=8 n-tiles/block, in-place deg ----------
// MODE0 (gi, KK=256): stage W[:,0:128] -> k-loop (A=hv) -> acc *= deg
// (f32, exact) -> stage W[:,128:256] -> k-loop (A=S) accumulates same acc.
// Final: gi = deg*accL + accR; epilogue adds bih + deg*c1.
// MODE1 (gh, KK=128): single stage, A=hv.
// split precision: acc += Ah*Wh + Al*Wh + Ah*Wl  (R4-R17 verified scheme).
// MFMA frag map (R4-R10 verified): A row = m0+wm+mt*16+lr, k = k0+quad*8;
//   B row = LDS row nt*16+lr, k = k0+quad*8; D col = lane&15, row = quad*4+reg.
template<int KK, int MODE, int NT>
__global__ __launch_bounds__(256) void gemm_t(
    const _Float16* __restrict__ AhA, const _Float16* __restrict__ AlA,
    const _Float16* __restrict__ AhB, const _Float16* __restrict__ AlB,
    const _Float16* __restrict__ Wh,  const _Float16* __restrict__ Wl,
    const float* __restrict__ bias, const float* __restrict__ bias2,
    _Float16* __restrict__ outC, const int* __restrict__ deg, int M) {
    constexpr int KH  = 128;       // per-stage K half (= HH)
    constexpr int LDW = KH + 8;
    constexpr int NST = KK / KH;   // 2 (gi) or 1 (gh)
    constexpr int NROWS = NT * 16; // 128
    constexpr int NTILES = 384 / NROWS;
    __shared__ _Float16 Wsh[NROWS][LDW];
    __shared__ _Float16 Wsl[NROWS][LDW];

    // bijective XCD-chunk swizzle (m204): hw round-robin -> contiguous wids
    int nwg = gridDim.x;
    int q = nwg >> 3, r = nwg & 7;
    int xcd = blockIdx.x & 7, pos = blockIdx.x >> 3;
    int wid = (xcd < r ? xcd * (q + 1) : r * (q + 1) + (xcd - r) * q) + pos;
    int n0 = (wid % NTILES) * NROWS;
    int m0 = (wid / NTILES) * 128;

    int tid = threadIdx.x;
    int wave = tid >> 6, lane = tid & 63;
    int lr = lane & 15, quad = lane >> 4;
    int wm = wave * 32;

    int gm[2]; bool vm[2];
    #pragma unroll
    for (int mt = 0; mt < 2; mt++) { gm[mt] = m0 + wm + mt * 16 + lr; vm[mt] = gm[mt] < M; }

    float dvr[2][4];
    #pragma unroll
    for (int mt = 0; mt < 2; mt++)
        #pragma unroll
        for (int rg = 0; rg < 4; rg++) {
            int m = m0 + wm + mt * 16 + quad * 4 + rg;
            dvr[mt][rg] = (MODE == 0 && m < M) ? (float)deg[m] : 0.f;
        }

    floatx4 acc[2][NT] = {};

    // W staging geometry: 16 threads/row, 16 rows/pass, NROWS/16 passes
    int srr = tid >> 4;
    int scc = (tid & 15) * 8;

    #pragma unroll
    for (int s = 0; s < NST; s++) {
        if (s > 0) __syncthreads();   // all waves done reading previous half
        #pragma unroll
        for (int base = 0; base < NROWS; base += 16) {
            int rw = base + srr;
            *(half8*)&Wsh[rw][scc] =
                *(const half8*)(Wh + (size_t)(n0 + rw) * KK + s * KH + scc);
            *(half8*)&Wsl[rw][scc] =
                *(const half8*)(Wl + (size_t)(n0 + rw) * KK + s * KH + scc);
        }
        __syncthreads();

        const bool leftStage = (MODE == 0) && (s == 0);
        const _Float16* Ph = leftStage ? AhA : AhB;
        const _Float16* Pl = leftStage ? AlA : AlB;

        #pragma unroll
        for (int k0 = 0; k0 < KH; k0 += 32) {
            int kk = k0 + quad * 8;
            half8 afh[2] = {}, afl[2] = {};
            #pragma unroll
            for (int mt = 0; mt < 2; mt++) if (vm[mt]) {
                afh[mt] = *(const half8*)(Ph + (size_t)gm[mt] * HH + kk);
                afl[mt] = *(const half8*)(Pl + (size_t)gm[mt] * HH + kk);
            }
            #pragma unroll
            for (int nt = 0; nt < NT; nt++) {
                half8 bh = *(const half8*)&Wsh[nt * 16 + lr][kk];
                half8 bl = *(const half8*)&Wsl[nt * 16 + lr][kk];
                #pragma unroll
                for (int mt = 0; mt < 2; mt++) {
                    acc[mt][nt] = __builtin_amdgcn_mfma_f32_16x16x32_f16(afh[mt], bh, acc[mt][nt], 0, 0, 0);
                    acc[mt][nt] = __builtin_amdgcn_mfma_f32_16x16x32_f16(afl[mt], bh, acc[mt][nt], 0, 0, 0);
                    acc[mt][nt] = __builtin_amdgcn_mfma_f32_16x16x32_f16(afh[mt], bl, acc[mt][nt], 0, 0, 0);
                }
            }
        }

        // in-place deg rescale between halves: gi = deg*accL + accR (exact f32)
        if (leftStage) {
            #pragma unroll
            for (int mt = 0; mt < 2; mt++)
                #pragma unroll
                for (int nt = 0; nt < NT; nt++)
                    #pragma unroll
                    for (int rg = 0; rg < 4; rg++)
                        acc[mt][nt][rg] *= dvr[mt][rg];
        }
    }

    // ---- epilogue ----
    #pragma unroll
    for (int mt = 0; mt < 2; mt++) {
        #pragma unroll
        for (int rg = 0; rg < 4; rg++) {
            int m = m0 + wm + mt * 16 + quad * 4 + rg;
            if (m >= M) continue;
            #pragma unroll
            for (int nt = 0; nt < NT; nt++) {
                int n = n0 + nt * 16 + lr;
                float v = acc[mt][nt][rg] + bias[n];
                if (MODE == 0) v += dvr[mt][rg] * bias2[n];
                outC[(size_t)m * 384 + n] = (_Float16)v;
            }
        }
    }
}

// ---------- fused GRU gates, half8-vectorized (R21-proven) ----------
__global__ void gate_kernel(const _Float16* __restrict__ gi,
                            const _Float16* __restrict__ gh,
                            _Float16* __restrict__ hvH, _Float16* __restrict__ hvL,
                            void* __restrict__ outv,
                            const int* __restrict__ flags, int writeOut, int total8) {
    int idx = blockIdx.x * blockDim.x + threadIdx.x;   // one thread per 8 cols
    if (idx >= total8) return;
    int n = idx >> 4;          // HH/8 = 16 chunks per node
    int jv = (idx & 15) * 8;   // column base within row
    size_t base = (size_t)n * 384 + jv;
    half8 ir  = *(const half8*)(gi + base);
    half8 iz  = *(const half8*)(gi + base + 128);
    half8 inn = *(const half8*)(gi + base + 256);
    half8 hr  = *(const half8*)(gh + base);
    half8 hz  = *(const half8*)(gh + base + 128);
    half8 hnn = *(const half8*)(gh + base + 256);
    size_t hbase = (size_t)n * HH + jv;
    half8 hH = *(const half8*)(hvH + hbase);
    half8 hL = *(const half8*)(hvL + hbase);
    half8 oH, oL;
    float outf[8];
    #pragma unroll
    for (int qv = 0; qv < 8; qv++) {
        float i_r = (float)ir[qv], i_z = (float)iz[qv], i_n = (float)inn[qv];
        float h_r = (float)hr[qv], h_z = (float)hz[qv], h_n = (float)hnn[qv];
        float h = (float)hH[qv] + (float)hL[qv];
        float r = 1.f / (1.f + __expf(-(i_r + h_r)));
        float z = 1.f / (1.f + __expf(-(i_z + h_z)));
        float nn = tanhf(i_n + r * h_n);
        float hn = (1.f - z) * nn + z * h;
        _Float16 hh = (_Float16)hn;
        oH[qv] = hh;
        oL[qv] = (_Float16)(hn - (float)hh);
        outf[qv] = hn;
    }
    *(half8*)(hvH + hbase) = oH;
    *(half8*)(hvL + hbase) = oL;
    if (writeOut) {
        if (flags[1]) {
            float* op = (float*)outv + hbase;
            #pragma unroll
            for (int qv = 0; qv < 8; qv++) op[qv] = outf[qv];
        } else {
            __hip_bfloat16* op = (__hip_bfloat16*)outv + hbase;
            #pragma unroll
            for (int qv = 0; qv < 8; qv++) op[qv] = __float2bfloat16(outf[qv]);
        }
    }
}

extern "C" void kernel_launch(void* const* d_in, const int* in_sizes, int n_in,
                              void* d_out, int out_size, void* d_ws, size_t ws_size,
                              hipStream_t stream) {
    const void* hv_in   = d_in[0];
    const int* edge_src = (const int*)d_in[1];
    const int* edge_dst = (const int*)d_in[2];
    const void* msg_W = d_in[3];
    const void* msg_b = d_in[4];
    const void* gWih  = d_in[5];
    const void* gWhh  = d_in[6];
    const void* gbih  = d_in[7];
    const void* gbhh  = d_in[8];

    // ---- workspace carve-up (~118 MB) ----
    char* p = (char*)d_ws;
    auto alloc = [&](size_t bytes) -> void* {
        void* r = (void*)p;
        p += (bytes + 255) & ~(size_t)255;
        return r;
    };
    int* flags   = (int*)alloc(256);
    int* deg     = (int*)alloc((size_t)NN * 4);
    int* row     = (int*)alloc((size_t)(NN + 1) * 4);
    int* counts  = (int*)alloc((size_t)GG * NB * 4);   // 3.2 MB, [g][b]
    int* bsum    = (int*)alloc((size_t)NB * 4);
    int* bbase   = (int*)alloc((size_t)(NB + 1) * 4);
    int* offsets = (int*)alloc((size_t)GG * NB * 4);   // 3.2 MB, [g][b]
    int* pairs   = (int*)alloc((size_t)NE * 4);        // becomes sorted csr
    _Float16* wCcH = (_Float16*)alloc((size_t)TT * 384 * 256 * 2);  // Wc hi
    _Float16* wCcL = (_Float16*)alloc((size_t)TT * 384 * 256 * 2);  // Wc lo
    _Float16* wHhH = (_Float16*)alloc((size_t)TT * 384 * 128 * 2);
    _Float16* wHhL = (_Float16*)alloc((size_t)TT * 384 * 128 * 2);
    float* bMsg = (float*)alloc((size_t)TT * 256 * 4);
    float* bIh  = (float*)alloc((size_t)TT * 384 * 4);
    float* bHh  = (float*)alloc((size_t)TT * 384 * 4);
    float* c1   = (float*)alloc((size_t)TT * 384 * 4);
    _Float16* hvH = (_Float16*)alloc((size_t)NN * HH * 2);   // 12.8 MB
    _Float16* hvL = (_Float16*)alloc((size_t)NN * HH * 2);   // 12.8 MB
    char* PA = (char*)alloc((size_t)NN * 384 * 2);           // 38.4 MB: gi
    char* PB = (char*)alloc((size_t)NN * 384 * 2);           // 38.4 MB: SH+SL -> gh
    (void)ws_size; (void)in_sizes; (void)n_in; (void)out_size;

    _Float16* gi = (_Float16*)PA;
    _Float16* SH = (_Float16*)PB;
    _Float16* SL = (_Float16*)(PB + (size_t)NN * HH * 2);
    _Float16* gh = (_Float16*)PB;   // overwrites dead S after gi-GEMM

    // ---- dtype detection + preprocessing ----
    detect_kernel<<<1, 64, 0, stream>>>((const unsigned short*)hv_in, edge_src, flags);
    split_kernel<<<(NN * HH + 255) / 256, 256, 0, stream>>>(hv_in, hvH, hvL, NN * HH, flags);
    split_kernel<<<(TT * 384 * 128 + 255) / 256, 256, 0, stream>>>(
        gWhh, wHhH, wHhL, TT * 384 * 128, flags);
    {
        int n1 = TT * 256, n2 = TT * 384, n3 = TT * 384;
        conv3_kernel<<<(n1 + n2 + n3 + 255) / 256, 256, 0, stream>>>(
            msg_b, bMsg, n1, gbih, bIh, n2, gbhh, bHh, n3, flags);
    }
    wc_kernel<<<TT * 384, 256, 0, stream>>>(gWih, msg_W, wCcH, wCcL, flags);
    c1_kernel<<<(TT * 384 + 63) / 64, 64, 0, stream>>>(gWih, bMsg, c1, flags);

    // ---- bucket-CSR build + in-bucket sort -> per-node CSR ----
    bucket_hist_kernel<<<GG, 256, 0, stream>>>(edge_dst, counts);
    bucket_sum_kernel<<<(NB + 3) / 4, 256, 0, stream>>>(counts, bsum);
    bucket_scan_kernel<<<1, 1024, 0, stream>>>(bsum, bbase);
    bucket_offsets_kernel<<<(NB + 3) / 4, 256, 0, stream>>>(counts, bbase, offsets);
    bucket_scatter_kernel<<<GG, 256, 0, stream>>>(edge_src, edge_dst, offsets, pairs, flags);
    bucket_sort_kernel<<<NB, 256, 0, stream>>>(bbase, pairs, row, deg);

    const int mt128 = (NN + 127) / 128;   // 391 m-tiles

    for (int t = 0; t < TT; t++) {
        // S planes from per-node 16-wide gather (-> PB)
        gather_kernel<<<NN, 64, 0, stream>>>(row, pairs, hvH, SH, SL);

        // gi = f16( deg*(WcL@hv + c1) + WcR@S + bih )  -> PA
        // NT=8: 3 n-tiles of 128; 1173 blocks; 69.6KB LDS -> 2 blocks/CU.
        gemm_t<256, 0, 8><<<mt128 * 3, 256, 0, stream>>>(
            hvH, hvL, SH, SL,
            wCcH + (size_t)t * 384 * 256, wCcL + (size_t)t * 384 * 256,
            bIh + (size_t)t * 384, c1 + (size_t)t * 384, gi, deg, NN);

        // gh = f16( Whh@hv + bhh )  -> PB (S dead now)
        gemm_t<128, 1, 8><<<mt128 * 3, 256, 0, stream>>>(
            hvH, hvL, hvH, hvL,
            wHhH + (size_t)t * 384 * 128, wHhL + (size_t)t * 384 * 128,
            bHh + (size_t)t * 384, nullptr, gh, deg, NN);

        // GRU gates (half8-vectorized); dtype-aware output on last round
        gate_kernel<<<(NN * 16 + 255) / 256, 256, 0, stream>>>(
            gi, gh, hvH, hvL, d_out, flags, (t == TT - 1) ? 1 : 0, NN * 16);
    }
}